// Round 1
// baseline (948.208 us; speedup 1.0000x reference)
//
#include <hip/hip_runtime.h>

// EdgewiseForcesSum: out[N,3] = segment_sum(edge_forces[E,3], edge_index[0])
// N = 100000, E = 6400000.
// d_in[0]: edge_forces float32, 3*E elements
// d_in[1]: edge_index  int32 (harness converts int64 -> int32), 2*E elements
// d_in[2]: atom_types  int32, N elements (only defines N; unused)
// d_out:   float32, 3*N elements

#define EFS_N_NODES 100000
#define EFS_N_EDGES 6400000

__global__ void efs_zero_kernel(float* __restrict__ out, int n) {
    int i = blockIdx.x * blockDim.x + threadIdx.x;
    if (i < n) out[i] = 0.0f;
}

__global__ void efs_scatter_kernel(const float4* __restrict__ ef4,   // edge_forces viewed as float4
                                   const int4*   __restrict__ ctr4,  // edge_center viewed as int4
                                   float* __restrict__ out,
                                   int n_quads) {                    // E/4
    int t = blockIdx.x * blockDim.x + threadIdx.x;
    if (t >= n_quads) return;

    // 4 edges per thread: 3 float4 = 12 floats = 4 edges' forces, 1 int4 = 4 centers.
    int4 c = ctr4[t];
    float4 a = ef4[t * 3 + 0];   // e0.x e0.y e0.z e1.x
    float4 b = ef4[t * 3 + 1];   // e1.y e1.z e2.x e2.y
    float4 d = ef4[t * 3 + 2];   // e2.z e3.x e3.y e3.z

    // edge 0
    atomicAdd(&out[c.x * 3 + 0], a.x);
    atomicAdd(&out[c.x * 3 + 1], a.y);
    atomicAdd(&out[c.x * 3 + 2], a.z);
    // edge 1
    atomicAdd(&out[c.y * 3 + 0], a.w);
    atomicAdd(&out[c.y * 3 + 1], b.x);
    atomicAdd(&out[c.y * 3 + 2], b.y);
    // edge 2
    atomicAdd(&out[c.z * 3 + 0], b.z);
    atomicAdd(&out[c.z * 3 + 1], b.w);
    atomicAdd(&out[c.z * 3 + 2], d.x);
    // edge 3
    atomicAdd(&out[c.w * 3 + 0], d.y);
    atomicAdd(&out[c.w * 3 + 1], d.z);
    atomicAdd(&out[c.w * 3 + 2], d.w);
}

extern "C" void kernel_launch(void* const* d_in, const int* in_sizes, int n_in,
                              void* d_out, int out_size, void* d_ws, size_t ws_size,
                              hipStream_t stream) {
    const float* edge_forces = (const float*)d_in[0];
    const int*   edge_index  = (const int*)d_in[1];   // [2, E] flat; row 0 = centers
    float*       out         = (float*)d_out;         // [N, 3] flat

    const int E = in_sizes[1] / 2;        // 6400000
    const int n_out = out_size;           // 3 * N = 300000

    // 1) zero the output (harness poisons d_out; we must re-init every call)
    {
        int threads = 256;
        int blocks = (n_out + threads - 1) / threads;
        efs_zero_kernel<<<blocks, threads, 0, stream>>>(out, n_out);
    }

    // 2) scatter-add, 4 edges per thread
    {
        int n_quads = E / 4;              // E divisible by 4
        int threads = 256;
        int blocks = (n_quads + threads - 1) / threads;
        efs_scatter_kernel<<<blocks, threads, 0, stream>>>(
            (const float4*)edge_forces,
            (const int4*)edge_index,      // row 0 starts at offset 0
            out, n_quads);
    }
}

// Round 2
// 136.193 us; speedup vs baseline: 6.9622x; 6.9622x over previous
//
#include <hip/hip_runtime.h>

// EdgewiseForcesSum: out[N,3] = segment_sum(edge_forces[E,3], edge_index[0])
// N = 100000, E = 6400000.
// Strategy: node-range binning. 8 bins x 12500 nodes; each block owns one
// (bin, edge-chunk) pair, accumulates matching edges into a 150 KB LDS
// accumulator (LDS atomics), then streams the bin slice to a per-chunk
// partial buffer in d_ws (NO global atomics). Phase 2 reduces partials.

#define EFS_N      100000
#define EFS_E      6400000
#define EFS_BINS   8
#define EFS_R      12500          // nodes per bin (8 * 12500 = 100000)
#define EFS_MAXP   32             // max chunks (partials)
#define EFS_N3     (EFS_N * 3)    // 300000
#define EFS_RF     (EFS_R * 3)    // floats per bin slice = 37500 (div by 4)

// ---------------- phase 1: bin + LDS accumulate + stream flush --------------
__global__ __launch_bounds__(1024) void efs_bin_kernel(
    const int* __restrict__ centers,      // edge_index row 0, E ints
    const float* __restrict__ ef,         // edge_forces, 3E floats
    float* __restrict__ partials,         // P x N3 floats in d_ws
    int P) {
    __shared__ float lds[EFS_RF];         // 150,000 B

    // chunk-major-in-low-bits: all 8 bins of chunk c share (c mod 8) -> same
    // XCD under round-robin dispatch -> chunk data reused from that XCD's L2.
    int c = blockIdx.x % P;               // chunk id
    int b = blockIdx.x / P;               // bin id

    // zero LDS (float4)
    float4* lds4 = (float4*)lds;
    for (int i = threadIdx.x; i < EFS_RF / 4; i += blockDim.x)
        lds4[i] = make_float4(0.f, 0.f, 0.f, 0.f);
    __syncthreads();

    const int binStart = b * EFS_R;
    const long e0 = (long)c * EFS_E / P;
    const long e1 = (long)(c + 1) * EFS_E / P;

    for (long e = e0 + threadIdx.x; e < e1; e += blockDim.x) {
        int ctr = centers[e];
        unsigned rel = (unsigned)(ctr - binStart);
        if (rel < (unsigned)EFS_R) {
            int fe = (int)e * 3;
            float fx = ef[fe + 0];
            float fy = ef[fe + 1];
            float fz = ef[fe + 2];
            int li = rel * 3;
            atomicAdd(&lds[li + 0], fx);
            atomicAdd(&lds[li + 1], fy);
            atomicAdd(&lds[li + 2], fz);
        }
    }
    __syncthreads();

    // flush bin slice -> partial c (pure streaming stores, float4)
    float4* dst = (float4*)(partials + (size_t)c * EFS_N3 + (size_t)binStart * 3);
    for (int i = threadIdx.x; i < EFS_RF / 4; i += blockDim.x)
        dst[i] = lds4[i];
}

// ---------------- phase 2: reduce P partials -> out -------------------------
__global__ void efs_reduce_kernel(const float4* __restrict__ partials,
                                  float4* __restrict__ out, int P) {
    const int n4 = EFS_N3 / 4;            // 75000
    int i = blockIdx.x * blockDim.x + threadIdx.x;
    if (i >= n4) return;
    float4 s = partials[i];
    for (int p = 1; p < P; ++p) {
        float4 v = partials[(size_t)p * n4 + i];
        s.x += v.x; s.y += v.y; s.z += v.z; s.w += v.w;
    }
    out[i] = s;
}

// ---------------- fallback (tiny ws): round-1 atomic scatter ----------------
__global__ void efs_zero_kernel(float* __restrict__ out, int n) {
    int i = blockIdx.x * blockDim.x + threadIdx.x;
    if (i < n) out[i] = 0.0f;
}

__global__ void efs_scatter_kernel(const float4* __restrict__ ef4,
                                   const int4* __restrict__ ctr4,
                                   float* __restrict__ out, int n_quads) {
    int t = blockIdx.x * blockDim.x + threadIdx.x;
    if (t >= n_quads) return;
    int4 c = ctr4[t];
    float4 a = ef4[t * 3 + 0];
    float4 b = ef4[t * 3 + 1];
    float4 d = ef4[t * 3 + 2];
    atomicAdd(&out[c.x * 3 + 0], a.x);
    atomicAdd(&out[c.x * 3 + 1], a.y);
    atomicAdd(&out[c.x * 3 + 2], a.z);
    atomicAdd(&out[c.y * 3 + 0], a.w);
    atomicAdd(&out[c.y * 3 + 1], b.x);
    atomicAdd(&out[c.y * 3 + 2], b.y);
    atomicAdd(&out[c.z * 3 + 0], b.z);
    atomicAdd(&out[c.z * 3 + 1], b.w);
    atomicAdd(&out[c.z * 3 + 2], d.x);
    atomicAdd(&out[c.w * 3 + 0], d.y);
    atomicAdd(&out[c.w * 3 + 1], d.z);
    atomicAdd(&out[c.w * 3 + 2], d.w);
}

extern "C" void kernel_launch(void* const* d_in, const int* in_sizes, int n_in,
                              void* d_out, int out_size, void* d_ws, size_t ws_size,
                              hipStream_t stream) {
    const float* edge_forces = (const float*)d_in[0];
    const int*   edge_index  = (const int*)d_in[1];   // row 0 = centers
    float*       out         = (float*)d_out;

    const int E = in_sizes[1] / 2;

    // partials needed: P * N3 * 4 bytes; pick largest P <= 32 that fits ws
    int P = (int)(ws_size / ((size_t)EFS_N3 * sizeof(float)));
    if (P > EFS_MAXP) P = EFS_MAXP;

    if (P >= 1) {
        float* partials = (float*)d_ws;
        dim3 grid1(EFS_BINS * P);
        efs_bin_kernel<<<grid1, 1024, 0, stream>>>(edge_index, edge_forces,
                                                   partials, P);
        int n4 = EFS_N3 / 4;
        int threads = 256;
        int blocks = (n4 + threads - 1) / threads;
        efs_reduce_kernel<<<blocks, threads, 0, stream>>>((const float4*)partials,
                                                          (float4*)out, P);
    } else {
        // scratch too small: atomic fallback
        int threads = 256;
        int blocks = (out_size + threads - 1) / threads;
        efs_zero_kernel<<<blocks, threads, 0, stream>>>(out, out_size);
        int n_quads = E / 4;
        blocks = (n_quads + threads - 1) / threads;
        efs_scatter_kernel<<<blocks, threads, 0, stream>>>(
            (const float4*)edge_forces, (const int4*)edge_index, out, n_quads);
    }
}

// Round 3
// 125.001 us; speedup vs baseline: 7.5856x; 1.0895x over previous
//
#include <hip/hip_runtime.h>

// EdgewiseForcesSum: out[N,3] = segment_sum(edge_forces[E,3], edge_index[0])
// N = 100000, E = 6400000.
// Node-range binning: 8 bins x 12500 nodes; block (bin b, chunk c) streams
// its 200K-edge chunk with UNCONDITIONAL vectorized loads (int4 centers +
// 3x float4 forces, 4 edges/thread/iter), accumulates matches into a 150 KB
// LDS accumulator via LDS atomics, then streams the bin slice to partial c
// in d_ws. Phase 2 reduces the 32 partials. No global atomics anywhere.
// All 8 bins of chunk c land on the same XCD (blockIdx%8 == c%8) so the 8x
// force re-read is served by that XCD's L2.

#define EFS_N      100000
#define EFS_E      6400000
#define EFS_BINS   8
#define EFS_R      12500          // nodes per bin
#define EFS_MAXP   32
#define EFS_N3     (EFS_N * 3)    // 300000
#define EFS_RF     (EFS_R * 3)    // 37500 floats = 150 KB

// ---------------- phase 1: bin + LDS accumulate + stream flush --------------
__global__ __launch_bounds__(1024) void efs_bin_kernel(
    const int4* __restrict__ ctr4,        // centers as int4 (E/4)
    const float4* __restrict__ ef4,       // forces as float4 (3E/4)
    float* __restrict__ partials,         // P x N3 floats in d_ws
    int P) {
    __shared__ float lds[EFS_RF];

    int c = blockIdx.x % P;               // chunk id  (c%8 selects XCD)
    int b = blockIdx.x / P;               // bin id

    float4* lds4 = (float4*)lds;
    for (int i = threadIdx.x; i < EFS_RF / 4; i += blockDim.x)
        lds4[i] = make_float4(0.f, 0.f, 0.f, 0.f);
    __syncthreads();

    const int binStart = b * EFS_R;
    const int q0 = (int)((long)c * EFS_E / P) / 4;        // quad range
    const int q1 = (int)((long)(c + 1) * EFS_E / P) / 4;

    #pragma unroll 2
    for (int q = q0 + threadIdx.x; q < q1; q += blockDim.x) {
        // 4 edges: all loads independent, issued before any use
        int4   cc = ctr4[q];
        float4 fa = ef4[3 * q + 0];   // e0.x e0.y e0.z e1.x
        float4 fb = ef4[3 * q + 1];   // e1.y e1.z e2.x e2.y
        float4 fd = ef4[3 * q + 2];   // e2.z e3.x e3.y e3.z

        unsigned r0 = (unsigned)(cc.x - binStart);
        unsigned r1 = (unsigned)(cc.y - binStart);
        unsigned r2 = (unsigned)(cc.z - binStart);
        unsigned r3 = (unsigned)(cc.w - binStart);

        if (r0 < (unsigned)EFS_R) {
            atomicAdd(&lds[r0 * 3 + 0], fa.x);
            atomicAdd(&lds[r0 * 3 + 1], fa.y);
            atomicAdd(&lds[r0 * 3 + 2], fa.z);
        }
        if (r1 < (unsigned)EFS_R) {
            atomicAdd(&lds[r1 * 3 + 0], fa.w);
            atomicAdd(&lds[r1 * 3 + 1], fb.x);
            atomicAdd(&lds[r1 * 3 + 2], fb.y);
        }
        if (r2 < (unsigned)EFS_R) {
            atomicAdd(&lds[r2 * 3 + 0], fb.z);
            atomicAdd(&lds[r2 * 3 + 1], fb.w);
            atomicAdd(&lds[r2 * 3 + 2], fd.x);
        }
        if (r3 < (unsigned)EFS_R) {
            atomicAdd(&lds[r3 * 3 + 0], fd.y);
            atomicAdd(&lds[r3 * 3 + 1], fd.z);
            atomicAdd(&lds[r3 * 3 + 2], fd.w);
        }
    }
    __syncthreads();

    float4* dst = (float4*)(partials + (size_t)c * EFS_N3 + (size_t)binStart * 3);
    for (int i = threadIdx.x; i < EFS_RF / 4; i += blockDim.x)
        dst[i] = lds4[i];
}

// ---------------- phase 2: reduce P partials -> out -------------------------
__global__ void efs_reduce_kernel(const float4* __restrict__ partials,
                                  float4* __restrict__ out, int P) {
    const int n4 = EFS_N3 / 4;            // 75000
    int i = blockIdx.x * blockDim.x + threadIdx.x;
    if (i >= n4) return;
    float4 s = partials[i];
    for (int p = 1; p < P; ++p) {
        float4 v = partials[(size_t)p * n4 + i];
        s.x += v.x; s.y += v.y; s.z += v.z; s.w += v.w;
    }
    out[i] = s;
}

// ---------------- fallback (tiny ws): atomic scatter ------------------------
__global__ void efs_zero_kernel(float* __restrict__ out, int n) {
    int i = blockIdx.x * blockDim.x + threadIdx.x;
    if (i < n) out[i] = 0.0f;
}

__global__ void efs_scatter_kernel(const float4* __restrict__ ef4,
                                   const int4* __restrict__ ctr4,
                                   float* __restrict__ out, int n_quads) {
    int t = blockIdx.x * blockDim.x + threadIdx.x;
    if (t >= n_quads) return;
    int4 c = ctr4[t];
    float4 a = ef4[t * 3 + 0];
    float4 b = ef4[t * 3 + 1];
    float4 d = ef4[t * 3 + 2];
    atomicAdd(&out[c.x * 3 + 0], a.x);
    atomicAdd(&out[c.x * 3 + 1], a.y);
    atomicAdd(&out[c.x * 3 + 2], a.z);
    atomicAdd(&out[c.y * 3 + 0], a.w);
    atomicAdd(&out[c.y * 3 + 1], b.x);
    atomicAdd(&out[c.y * 3 + 2], b.y);
    atomicAdd(&out[c.z * 3 + 0], b.z);
    atomicAdd(&out[c.z * 3 + 1], b.w);
    atomicAdd(&out[c.z * 3 + 2], d.x);
    atomicAdd(&out[c.w * 3 + 0], d.y);
    atomicAdd(&out[c.w * 3 + 1], d.z);
    atomicAdd(&out[c.w * 3 + 2], d.w);
}

extern "C" void kernel_launch(void* const* d_in, const int* in_sizes, int n_in,
                              void* d_out, int out_size, void* d_ws, size_t ws_size,
                              hipStream_t stream) {
    const float* edge_forces = (const float*)d_in[0];
    const int*   edge_index  = (const int*)d_in[1];   // row 0 = centers
    float*       out         = (float*)d_out;

    const int E = in_sizes[1] / 2;

    int P = (int)(ws_size / ((size_t)EFS_N3 * sizeof(float)));
    if (P > EFS_MAXP) P = EFS_MAXP;

    if (P >= 1) {
        float* partials = (float*)d_ws;
        dim3 grid1(EFS_BINS * P);
        efs_bin_kernel<<<grid1, 1024, 0, stream>>>(
            (const int4*)edge_index, (const float4*)edge_forces, partials, P);
        int n4 = EFS_N3 / 4;
        int threads = 256;
        int blocks = (n4 + threads - 1) / threads;
        efs_reduce_kernel<<<blocks, threads, 0, stream>>>((const float4*)partials,
                                                          (float4*)out, P);
    } else {
        int threads = 256;
        int blocks = (out_size + threads - 1) / threads;
        efs_zero_kernel<<<blocks, threads, 0, stream>>>(out, out_size);
        int n_quads = E / 4;
        blocks = (n_quads + threads - 1) / threads;
        efs_scatter_kernel<<<blocks, threads, 0, stream>>>(
            (const float4*)edge_forces, (const int4*)edge_index, out, n_quads);
    }
}